// Round 2
// baseline (382.855 us; speedup 1.0000x reference)
//
#include <hip/hip_runtime.h>
#include <stdint.h>

#define NB 8
#define NC 2048
#define ND 768
#define CD (NC * ND)  // 1572864
#define EPSV 1e-5f

typedef _Float16 f16;
typedef f16 f16x2 __attribute__((ext_vector_type(2)));
typedef f16 f16x8 __attribute__((ext_vector_type(8)));
typedef float f32x4 __attribute__((ext_vector_type(4)));
typedef unsigned short u16;
typedef unsigned int u32;
typedef u32 u32x2 __attribute__((ext_vector_type(2)));
typedef u32 u32x4 __attribute__((ext_vector_type(4)));

__device__ __forceinline__ u16 f2h(float f) {
  return __builtin_bit_cast(u16, (f16)f);  // v_cvt_f16_f32, RNE
}
__device__ __forceinline__ u32 pack2(float a, float b) {
  f16x2 h = {(f16)a, (f16)b};
  return __builtin_bit_cast(u32, h);
}

__device__ __forceinline__ float wave_sum(float v) {
#pragma unroll
  for (int o = 32; o > 0; o >>= 1) v += __shfl_down(v, o);
  return v;
}
__device__ __forceinline__ float wave_max(float v) {
#pragma unroll
  for (int o = 32; o > 0; o >>= 1) v = fmaxf(v, __shfl_down(v, o));
  return v;
}

// ---------------- LayerNorm over [C,D] per batch ----------------
__global__ __launch_bounds__(256) void ln_stats(const float* __restrict__ x,
                                                float* __restrict__ stats) {
  const int b = blockIdx.y;
  const float4* xb = (const float4*)(x + (size_t)b * CD);
  const int base = blockIdx.x * 6144;  // CD/4/64 blocks = 6144 float4 per block
  float s1 = 0.f, s2 = 0.f;
  for (int i = threadIdx.x; i < 6144; i += 256) {
    float4 v = xb[base + i];
    s1 += (v.x + v.y) + (v.z + v.w);
    s2 += (v.x * v.x + v.y * v.y) + (v.z * v.z + v.w * v.w);
  }
  s1 = wave_sum(s1);
  s2 = wave_sum(s2);
  __shared__ float r1[4], r2[4];
  const int lane = threadIdx.x & 63, w = threadIdx.x >> 6;
  if (lane == 0) { r1[w] = s1; r2[w] = s2; }
  __syncthreads();
  if (threadIdx.x == 0) {
    atomicAdd(&stats[b * 2], (r1[0] + r1[1]) + (r1[2] + r1[3]));
    atomicAdd(&stats[b * 2 + 1], (r2[0] + r2[1]) + (r2[2] + r2[3]));
  }
}

__global__ __launch_bounds__(256) void ln_apply(const float* __restrict__ x,
                                                const float* __restrict__ stats,
                                                u16* __restrict__ xn) {
  const size_t i = ((size_t)blockIdx.x * 256 + threadIdx.x) * 8;
  const int b = (int)(i / CD);
  const float mean = stats[b * 2] * (1.f / CD);
  const float var = stats[b * 2 + 1] * (1.f / CD) - mean * mean;
  const float rstd = rsqrtf(var + EPSV);
  const float4 v0 = *(const float4*)(x + i);
  const float4 v1 = *(const float4*)(x + i + 4);
  u32x4 p;
  p.x = pack2((v0.x - mean) * rstd, (v0.y - mean) * rstd);
  p.y = pack2((v0.z - mean) * rstd, (v0.w - mean) * rstd);
  p.z = pack2((v1.x - mean) * rstd, (v1.y - mean) * rstd);
  p.w = pack2((v1.z - mean) * rstd, (v1.w - mean) * rstd);
  *(u32x4*)(xn + i) = p;
}

__global__ __launch_bounds__(256) void cast_w(const float* __restrict__ Wk,
                                              const float* __restrict__ Wq,
                                              const float* __restrict__ Wv,
                                              u16* __restrict__ Wb) {
  const size_t i = ((size_t)blockIdx.x * 256 + threadIdx.x) * 8;
  const size_t WSZ = (size_t)ND * ND;
  const float* src;
  size_t off;
  if (i < WSZ) { src = Wk; off = i; }
  else if (i < 2 * WSZ) { src = Wq; off = i - WSZ; }
  else { src = Wv; off = i - 2 * WSZ; }
  const float4 v0 = *(const float4*)(src + off);
  const float4 v1 = *(const float4*)(src + off + 4);
  u32x4 p;
  p.x = pack2(v0.x, v0.y);
  p.y = pack2(v0.z, v0.w);
  p.z = pack2(v1.x, v1.y);
  p.w = pack2(v1.z, v1.w);
  *(u32x4*)(Wb + i) = p;
}

// ---------------- GEMM core: C[128x128] += A[128xK] * B[128xK]^T (f16, NT) ----------------
__device__ __forceinline__ void stage_tile(u16* lds, const u16* g, int lda, int tid) {
#pragma unroll
  for (int i = 0; i < 2; ++i) {
    const int s = tid + i * 256;  // 512 segments of 16B: 128 rows x 32 cols f16
    const u16* gp = g + (size_t)(s >> 2) * lda + (s & 3) * 8;
    __builtin_amdgcn_global_load_lds(
        (const __attribute__((address_space(1))) void*)gp,
        (__attribute__((address_space(3))) void*)(lds + s * 8), 16, 0, 0);
  }
}

__device__ __forceinline__ void gemm_core(const u16* __restrict__ Ab, int lda,
                                          const u16* __restrict__ Bb, int ldb, int nk,
                                          u16 (*ldsA)[4096], u16 (*ldsB)[4096], int tid,
                                          f32x4 acc[4][4]) {
  stage_tile(ldsA[0], Ab, lda, tid);
  stage_tile(ldsB[0], Bb, ldb, tid);
  const int lane = tid & 63, w = tid >> 6;
  const int wr = w >> 1, wc = w & 1;
  const int fr = lane & 15;
  const int ko = (lane >> 4) * 8;
  const int aoff = (wr * 64 + fr) * 32 + ko;
  const int boff = (wc * 64 + fr) * 32 + ko;
  __syncthreads();
  int cur = 0;
  for (int kt = 0; kt < nk; ++kt) {
    if (kt + 1 < nk) {
      stage_tile(ldsA[cur ^ 1], Ab + (size_t)(kt + 1) * 32, lda, tid);
      stage_tile(ldsB[cur ^ 1], Bb + (size_t)(kt + 1) * 32, ldb, tid);
    }
    f16x8 av[4], bv[4];
#pragma unroll
    for (int m = 0; m < 4; ++m) av[m] = *(const f16x8*)&ldsA[cur][aoff + m * 512];
#pragma unroll
    for (int n = 0; n < 4; ++n) bv[n] = *(const f16x8*)&ldsB[cur][boff + n * 512];
#pragma unroll
    for (int m = 0; m < 4; ++m)
#pragma unroll
      for (int n = 0; n < 4; ++n)
        acc[m][n] = __builtin_amdgcn_mfma_f32_16x16x32_f16(av[m], bv[n], acc[m][n], 0, 0, 0);
    __syncthreads();
    cur ^= 1;
  }
}

// z=0: K out (f16 row-major), z=1: Q out, z=2: V out TRANSPOSED -> Vt[b][d][c]
__global__ __launch_bounds__(256, 2) void gemm_proj(const u16* __restrict__ xn,
                                                    const u16* __restrict__ Wb,
                                                    u16* __restrict__ Kb,
                                                    u16* __restrict__ Qb,
                                                    u16* __restrict__ Vt) {
  __shared__ u16 ldsA[2][4096];
  __shared__ u16 ldsB[2][4096];
  const int tid = threadIdx.x;
  const int brow = blockIdx.x * 128;
  const int bcol = blockIdx.y * 128;
  const int z = blockIdx.z;
  const u16* Ab = xn + (size_t)brow * ND;
  const u16* Bb = Wb + (size_t)z * ND * ND + (size_t)bcol * ND;
  f32x4 acc[4][4] = {};
  gemm_core(Ab, ND, Bb, ND, ND / 32, ldsA, ldsB, tid, acc);
  const int lane = tid & 63, w = tid >> 6, wr = w >> 1, wc = w & 1;
  const int r0 = brow + wr * 64 + ((lane >> 4) << 2);
  const int c0 = bcol + wc * 64 + (lane & 15);
  if (z < 2) {
    u16* O = (z == 0) ? Kb : Qb;
#pragma unroll
    for (int m = 0; m < 4; ++m)
#pragma unroll
      for (int n = 0; n < 4; ++n)
#pragma unroll
        for (int q = 0; q < 4; ++q)
          O[(size_t)(r0 + m * 16 + q) * ND + (c0 + n * 16)] = f2h(acc[m][n][q]);
  } else {
    const int bb = r0 >> 11;    // batch
    const int cc = r0 & 2047;   // row within batch (4 consecutive -> contiguous in Vt)
#pragma unroll
    for (int m = 0; m < 4; ++m)
#pragma unroll
      for (int n = 0; n < 4; ++n) {
        u32x2 p;
        p.x = pack2(acc[m][n][0], acc[m][n][1]);
        p.y = pack2(acc[m][n][2], acc[m][n][3]);
        u16* dst = Vt + ((size_t)bb * ND + (c0 + n * 16)) * NC + (cc + m * 16);
        *(u32x2*)dst = p;
      }
  }
}

__global__ __launch_bounds__(256, 2) void gemm_qk(const u16* __restrict__ Qb,
                                                  const u16* __restrict__ Kb,
                                                  float* __restrict__ S) {
  __shared__ u16 ldsA[2][4096];
  __shared__ u16 ldsB[2][4096];
  const int tid = threadIdx.x;
  const int bz = blockIdx.z;
  const u16* Ab = Qb + ((size_t)bz * NC + blockIdx.x * 128) * ND;
  const u16* Bb = Kb + ((size_t)bz * NC + blockIdx.y * 128) * ND;
  float* Sb = S + (size_t)bz * NC * NC;
  f32x4 acc[4][4] = {};
  gemm_core(Ab, ND, Bb, ND, ND / 32, ldsA, ldsB, tid, acc);
  const int lane = tid & 63, w = tid >> 6, wr = w >> 1, wc = w & 1;
  const int r0 = blockIdx.x * 128 + wr * 64 + ((lane >> 4) << 2);
  const int c0 = blockIdx.y * 128 + wc * 64 + (lane & 15);
#pragma unroll
  for (int m = 0; m < 4; ++m)
#pragma unroll
    for (int n = 0; n < 4; ++n)
#pragma unroll
      for (int q = 0; q < 4; ++q)
        Sb[(size_t)(r0 + m * 16 + q) * NC + (c0 + n * 16)] = acc[m][n][q];
}

// softmax over each row of S (2048 f32); write f16 att in-place (row stride 4096 u16)
__global__ __launch_bounds__(256) void softmax_rows(float* __restrict__ S) {
  float* Sr = S + (size_t)blockIdx.x * NC;
  const int t = threadIdx.x;
  const float4* Sv = (const float4*)Sr;
  const float4 v0 = Sv[2 * t];
  const float4 v1 = Sv[2 * t + 1];
  float mv = fmaxf(fmaxf(fmaxf(v0.x, v0.y), fmaxf(v0.z, v0.w)),
                   fmaxf(fmaxf(v1.x, v1.y), fmaxf(v1.z, v1.w)));
  mv = wave_max(mv);
  __shared__ float rm[4], rs[4];
  const int lane = t & 63, w = t >> 6;
  if (lane == 0) rm[w] = mv;
  __syncthreads();  // also guarantees all reads of Sr are complete before in-place writes
  const float bm = fmaxf(fmaxf(rm[0], rm[1]), fmaxf(rm[2], rm[3]));
  const float e0 = __expf(v0.x - bm), e1 = __expf(v0.y - bm);
  const float e2 = __expf(v0.z - bm), e3 = __expf(v0.w - bm);
  const float e4 = __expf(v1.x - bm), e5 = __expf(v1.y - bm);
  const float e6 = __expf(v1.z - bm), e7 = __expf(v1.w - bm);
  float s = ((e0 + e1) + (e2 + e3)) + ((e4 + e5) + (e6 + e7));
  s = wave_sum(s);
  if (lane == 0) rs[w] = s;
  __syncthreads();
  const float inv = 1.f / ((rs[0] + rs[1]) + (rs[2] + rs[3]));
  u32x4 p;
  p.x = pack2(e0 * inv, e1 * inv);
  p.y = pack2(e2 * inv, e3 * inv);
  p.z = pack2(e4 * inv, e5 * inv);
  p.w = pack2(e6 * inv, e7 * inv);
  u16* ar = (u16*)Sr;
  *(u32x4*)(ar + t * 8) = p;
}

// out[b,i,d] = sum_j att[b,i,j] * Vt[b,d,j]   (A: att f16, lda=4096; B: Vt, ldb=2048)
__global__ __launch_bounds__(256, 2) void gemm_av(const u16* __restrict__ att,
                                                  const u16* __restrict__ Vt,
                                                  float* __restrict__ out) {
  __shared__ u16 ldsA[2][4096];
  __shared__ u16 ldsB[2][4096];
  const int tid = threadIdx.x;
  const int bz = blockIdx.z;
  const u16* Ab = att + (size_t)bz * NC * (NC * 2) + (size_t)(blockIdx.x * 128) * (NC * 2);
  const u16* Bb = Vt + ((size_t)bz * ND + blockIdx.y * 128) * NC;
  float* Ob = out + (size_t)bz * NC * ND;
  f32x4 acc[4][4] = {};
  gemm_core(Ab, NC * 2, Bb, NC, NC / 32, ldsA, ldsB, tid, acc);
  const int lane = tid & 63, w = tid >> 6, wr = w >> 1, wc = w & 1;
  const int r0 = blockIdx.x * 128 + wr * 64 + ((lane >> 4) << 2);
  const int c0 = blockIdx.y * 128 + wc * 64 + (lane & 15);
#pragma unroll
  for (int m = 0; m < 4; ++m)
#pragma unroll
    for (int n = 0; n < 4; ++n)
#pragma unroll
      for (int q = 0; q < 4; ++q)
        Ob[(size_t)(r0 + m * 16 + q) * ND + (c0 + n * 16)] = acc[m][n][q];
}

extern "C" void kernel_launch(void* const* d_in, const int* in_sizes, int n_in,
                              void* d_out, int out_size, void* d_ws, size_t ws_size,
                              hipStream_t stream) {
  (void)in_sizes; (void)n_in; (void)out_size; (void)ws_size;
  const float* x = (const float*)d_in[0];
  const float* Wk = (const float*)d_in[1];
  const float* Wq = (const float*)d_in[2];
  const float* Wv = (const float*)d_in[3];
  char* ws = (char*)d_ws;
  // workspace layout (bytes), all 256-aligned:
  float* stats = (float*)ws;                    //        64 B
  u16* xn = (u16*)(ws + 256);                   //  25165824
  u16* Wb = (u16*)(ws + 25166080);              //   3538944
  u16* Qb = (u16*)(ws + 28705024);              //  25165824
  u16* Kb = (u16*)(ws + 53870848);              //  25165824
  u16* Vt = (u16*)(ws + 79036672);              //  25165824
  float* S = (float*)(ws + 104202496);          // 134217728 (end 238420224)
  float* out = (float*)d_out;

  hipMemsetAsync(stats, 0, 64, stream);
  ln_stats<<<dim3(64, 8), 256, 0, stream>>>(x, stats);
  ln_apply<<<6144, 256, 0, stream>>>(x, stats, xn);
  cast_w<<<864, 256, 0, stream>>>(Wk, Wq, Wv, Wb);
  gemm_proj<<<dim3(128, 6, 3), 256, 0, stream>>>(xn, Wb, Kb, Qb, Vt);
  gemm_qk<<<dim3(16, 16, 8), 256, 0, stream>>>(Qb, Kb, S);
  softmax_rows<<<16384, 256, 0, stream>>>(S);
  gemm_av<<<dim3(16, 6, 8), 256, 0, stream>>>((const u16*)S, Vt, out);
}

// Round 3
// 367.938 us; speedup vs baseline: 1.0405x; 1.0405x over previous
//
#include <hip/hip_runtime.h>
#include <stdint.h>

#define NB 8
#define NC 2048
#define ND 768
#define CD (NC * ND)  // 1572864
#define EPSV 1e-5f

typedef _Float16 f16;
typedef f16 f16x2 __attribute__((ext_vector_type(2)));
typedef f16 f16x8 __attribute__((ext_vector_type(8)));
typedef float f32x4 __attribute__((ext_vector_type(4)));
typedef unsigned short u16;
typedef unsigned int u32;
typedef u32 u32x2 __attribute__((ext_vector_type(2)));
typedef u32 u32x4 __attribute__((ext_vector_type(4)));

__device__ __forceinline__ u16 f2h(float f) {
  return __builtin_bit_cast(u16, (f16)f);  // v_cvt_f16_f32, RNE
}
__device__ __forceinline__ u32 pack2(float a, float b) {
  f16x2 h = {(f16)a, (f16)b};
  return __builtin_bit_cast(u32, h);
}

__device__ __forceinline__ float wave_sum(float v) {
#pragma unroll
  for (int o = 32; o > 0; o >>= 1) v += __shfl_down(v, o);
  return v;
}
__device__ __forceinline__ float wave_max(float v) {
#pragma unroll
  for (int o = 32; o > 0; o >>= 1) v = fmaxf(v, __shfl_down(v, o));
  return v;
}

// ---------------- LayerNorm over [C,D] per batch ----------------
__global__ __launch_bounds__(256) void ln_stats(const float* __restrict__ x,
                                                float* __restrict__ stats) {
  const int b = blockIdx.y;
  const float4* xb = (const float4*)(x + (size_t)b * CD);
  const int base = blockIdx.x * 6144;
  float s1 = 0.f, s2 = 0.f;
  for (int i = threadIdx.x; i < 6144; i += 256) {
    float4 v = xb[base + i];
    s1 += (v.x + v.y) + (v.z + v.w);
    s2 += (v.x * v.x + v.y * v.y) + (v.z * v.z + v.w * v.w);
  }
  s1 = wave_sum(s1);
  s2 = wave_sum(s2);
  __shared__ float r1[4], r2[4];
  const int lane = threadIdx.x & 63, w = threadIdx.x >> 6;
  if (lane == 0) { r1[w] = s1; r2[w] = s2; }
  __syncthreads();
  if (threadIdx.x == 0) {
    atomicAdd(&stats[b * 2], (r1[0] + r1[1]) + (r1[2] + r1[3]));
    atomicAdd(&stats[b * 2 + 1], (r2[0] + r2[1]) + (r2[2] + r2[3]));
  }
}

__global__ __launch_bounds__(256) void ln_apply(const float* __restrict__ x,
                                                const float* __restrict__ stats,
                                                u16* __restrict__ xn) {
  const size_t i = ((size_t)blockIdx.x * 256 + threadIdx.x) * 8;
  const int b = (int)(i / CD);
  const float mean = stats[b * 2] * (1.f / CD);
  const float var = stats[b * 2 + 1] * (1.f / CD) - mean * mean;
  const float rstd = rsqrtf(var + EPSV);
  const float4 v0 = *(const float4*)(x + i);
  const float4 v1 = *(const float4*)(x + i + 4);
  u32x4 p;
  p.x = pack2((v0.x - mean) * rstd, (v0.y - mean) * rstd);
  p.y = pack2((v0.z - mean) * rstd, (v0.w - mean) * rstd);
  p.z = pack2((v1.x - mean) * rstd, (v1.y - mean) * rstd);
  p.w = pack2((v1.z - mean) * rstd, (v1.w - mean) * rstd);
  *(u32x4*)(xn + i) = p;
}

__global__ __launch_bounds__(256) void cast_w(const float* __restrict__ Wk,
                                              const float* __restrict__ Wq,
                                              const float* __restrict__ Wv,
                                              u16* __restrict__ Wb) {
  const size_t i = ((size_t)blockIdx.x * 256 + threadIdx.x) * 8;
  const size_t WSZ = (size_t)ND * ND;
  const float* src;
  size_t off;
  if (i < WSZ) { src = Wk; off = i; }
  else if (i < 2 * WSZ) { src = Wq; off = i - WSZ; }
  else { src = Wv; off = i - 2 * WSZ; }
  const float4 v0 = *(const float4*)(src + off);
  const float4 v1 = *(const float4*)(src + off + 4);
  u32x4 p;
  p.x = pack2(v0.x, v0.y);
  p.y = pack2(v0.z, v0.w);
  p.z = pack2(v1.x, v1.y);
  p.w = pack2(v1.z, v1.w);
  *(u32x4*)(Wb + i) = p;
}

// ======== 256x256-tile, BK=64, 8-wave, counted-vmcnt pipelined GEMM core (NT) ========
// LDS: lds[buf][op][chunk][4096 u16]; chunk = kk*2 + h. Each chunk: [128 rows][4 slots of 16B],
// slot swizzled: data G[rl][s] lives at slot s ^ ((rl>>1)&3)  (2-way banks = free, m136).
__device__ __forceinline__ void stage_chunk(u16* dst, const u16* src, int ld, int tid) {
  const int rl = tid >> 2;
  const int sc = (tid & 3) ^ ((tid >> 3) & 3);  // inverse swizzle applied on global source
  const u16* gp = src + (size_t)rl * ld + sc * 8;
  __builtin_amdgcn_global_load_lds(
      (const __attribute__((address_space(1))) void*)gp,
      (__attribute__((address_space(3))) void*)(dst + tid * 8), 16, 0, 0);
}

__device__ __forceinline__ void mf16(f32x4 acc[8][4], int mb, const f16x8 a[4],
                                     const f16x8 b[4]) {
#pragma unroll
  for (int m = 0; m < 4; ++m)
#pragma unroll
    for (int n = 0; n < 4; ++n)
      acc[mb + m][n] =
          __builtin_amdgcn_mfma_f32_16x16x32_f16(a[m], b[n], acc[mb + m][n], 0, 0, 0);
}

// Per-wave C: rows (mm>>2)*128 + wr*64 + (mm&3)*16, cols (nn>>1)*128 + wc*32 + (nn&1)*16.
__device__ __forceinline__ void gemm256(const u16* __restrict__ A, int lda,
                                        const u16* __restrict__ B, int ldb, int nk,
                                        u16 (*lds)[2][4][4096], int tid,
                                        f32x4 acc[8][4]) {
  const int lane = tid & 63;
  const int wc = (tid >> 6) & 3;
  const int wr = (tid >> 8) & 1;
  const int fr = lane & 15;
  const int SL = (lane >> 4) ^ ((lane >> 1) & 3);  // swizzled 16B-slot, rl-low-bits folded in
  int aoff[4], boff[4];
#pragma unroll
  for (int m = 0; m < 4; ++m) aoff[m] = (wr * 64 + m * 16 + fr) * 32 + SL * 8;
#pragma unroll
  for (int n = 0; n < 4; ++n) boff[n] = (wc * 32 + (n & 1) * 16 + fr) * 32 + SL * 8;

#define STG_A(BUF, T, KK)                                                  \
  do {                                                                     \
    const u16* s_ = A + (size_t)(T) * 64 + (KK) * 32;                      \
    stage_chunk(&lds[BUF][0][(KK) * 2 + 0][0], s_, lda, tid);              \
    stage_chunk(&lds[BUF][0][(KK) * 2 + 1][0], s_ + (size_t)128 * lda, lda, tid); \
  } while (0)
#define STG_B(BUF, T, KK)                                                  \
  do {                                                                     \
    const u16* s_ = B + (size_t)(T) * 64 + (KK) * 32;                      \
    stage_chunk(&lds[BUF][1][(KK) * 2 + 0][0], s_, ldb, tid);              \
    stage_chunk(&lds[BUF][1][(KK) * 2 + 1][0], s_ + (size_t)128 * ldb, ldb, tid); \
  } while (0)

  // prologue: tile 0 -> buf 0, issue order = [A kk0 | B kk0 | A kk1 | B kk1]
  STG_A(0, 0, 0); STG_B(0, 0, 0); STG_A(0, 0, 1); STG_B(0, 0, 1);

  for (int t = 0; t < nk; ++t) {
    const int cur = t & 1, nb = cur ^ 1;
    const bool pre = (t + 1 < nk);
    f16x8 a[4], b0[4], b1[4];
    // ---- P0: (mh0, kk0) — needs tile t's first 4 chunks ----
    asm volatile("s_waitcnt vmcnt(4)" ::: "memory");
    __builtin_amdgcn_s_barrier();
    __builtin_amdgcn_sched_barrier(0);
    if (pre) STG_A(nb, t + 1, 0);
#pragma unroll
    for (int m = 0; m < 4; ++m) a[m] = *(const f16x8*)&lds[cur][0][0][aoff[m]];
    b0[0] = *(const f16x8*)&lds[cur][1][0][boff[0]];
    b0[1] = *(const f16x8*)&lds[cur][1][0][boff[1]];
    b0[2] = *(const f16x8*)&lds[cur][1][1][boff[2]];
    b0[3] = *(const f16x8*)&lds[cur][1][1][boff[3]];
    __builtin_amdgcn_s_setprio(1);
    mf16(acc, 0, a, b0);
    __builtin_amdgcn_s_setprio(0);
    // ---- P1: (mh1, kk0) ----
    if (pre) STG_B(nb, t + 1, 0);
#pragma unroll
    for (int m = 0; m < 4; ++m) a[m] = *(const f16x8*)&lds[cur][0][1][aoff[m]];
    __builtin_amdgcn_s_setprio(1);
    mf16(acc, 4, a, b0);
    __builtin_amdgcn_s_setprio(0);
    // ---- P2: (mh1, kk1) — needs tile t's last 4 chunks ----
    if (pre) { asm volatile("s_waitcnt vmcnt(4)" ::: "memory"); }
    else     { asm volatile("s_waitcnt vmcnt(0)" ::: "memory"); }
    __builtin_amdgcn_s_barrier();
    __builtin_amdgcn_sched_barrier(0);
    if (pre) STG_A(nb, t + 1, 1);
#pragma unroll
    for (int m = 0; m < 4; ++m) a[m] = *(const f16x8*)&lds[cur][0][3][aoff[m]];
    b1[0] = *(const f16x8*)&lds[cur][1][2][boff[0]];
    b1[1] = *(const f16x8*)&lds[cur][1][2][boff[1]];
    b1[2] = *(const f16x8*)&lds[cur][1][3][boff[2]];
    b1[3] = *(const f16x8*)&lds[cur][1][3][boff[3]];
    __builtin_amdgcn_s_setprio(1);
    mf16(acc, 4, a, b1);
    __builtin_amdgcn_s_setprio(0);
    // ---- P3: (mh0, kk1) ----
    if (pre) STG_B(nb, t + 1, 1);
#pragma unroll
    for (int m = 0; m < 4; ++m) a[m] = *(const f16x8*)&lds[cur][0][2][aoff[m]];
    __builtin_amdgcn_s_setprio(1);
    mf16(acc, 0, a, b1);
    __builtin_amdgcn_s_setprio(0);
  }
#undef STG_A
#undef STG_B
}

// z=0: K out, z=1: Q out, z=2: V out TRANSPOSED -> Vt[b][d][c]
__global__ __launch_bounds__(512, 1) void gemm_proj(const u16* __restrict__ xn,
                                                    const u16* __restrict__ Wb,
                                                    u16* __restrict__ Kb,
                                                    u16* __restrict__ Qb,
                                                    u16* __restrict__ Vt) {
  __shared__ u16 lds[2][2][4][4096];
  const int tid = threadIdx.x;
  const int brow = blockIdx.x * 256;
  const int bcol = blockIdx.y * 256;
  const int z = blockIdx.z;
  f32x4 acc[8][4] = {};
  gemm256(xn + (size_t)brow * ND, ND, Wb + (size_t)z * ND * ND + (size_t)bcol * ND, ND,
          ND / 64, lds, tid, acc);
  const int lane = tid & 63, wc = (tid >> 6) & 3, wr = (tid >> 8) & 1;
  if (z < 2) {
    u16* O = (z == 0) ? Kb : Qb;
#pragma unroll
    for (int mm = 0; mm < 8; ++mm) {
      const int r = brow + (mm >> 2) * 128 + wr * 64 + (mm & 3) * 16 + ((lane >> 4) << 2);
#pragma unroll
      for (int nn = 0; nn < 4; ++nn) {
        const int c = bcol + (nn >> 1) * 128 + wc * 32 + (nn & 1) * 16 + (lane & 15);
#pragma unroll
        for (int q = 0; q < 4; ++q) O[(size_t)(r + q) * ND + c] = f2h(acc[mm][nn][q]);
      }
    }
  } else {
#pragma unroll
    for (int mm = 0; mm < 8; ++mm) {
      const int r = brow + (mm >> 2) * 128 + wr * 64 + (mm & 3) * 16 + ((lane >> 4) << 2);
      const int bb = r >> 11;
      const int cc = r & 2047;
#pragma unroll
      for (int nn = 0; nn < 4; ++nn) {
        const int c = bcol + (nn >> 1) * 128 + wc * 32 + (nn & 1) * 16 + (lane & 15);
        u32x2 p;
        p.x = pack2(acc[mm][nn][0], acc[mm][nn][1]);
        p.y = pack2(acc[mm][nn][2], acc[mm][nn][3]);
        *(u32x2*)(Vt + ((size_t)bb * ND + c) * NC + cc) = p;
      }
    }
  }
}

__global__ __launch_bounds__(512, 1) void gemm_qk(const u16* __restrict__ Qb,
                                                  const u16* __restrict__ Kb,
                                                  float* __restrict__ S) {
  __shared__ u16 lds[2][2][4][4096];
  const int tid = threadIdx.x;
  const int bz = blockIdx.z;
  f32x4 acc[8][4] = {};
  gemm256(Qb + ((size_t)bz * NC + blockIdx.x * 256) * ND, ND,
          Kb + ((size_t)bz * NC + blockIdx.y * 256) * ND, ND, ND / 64, lds, tid, acc);
  float* Sb = S + (size_t)bz * NC * NC;
  const int lane = tid & 63, wc = (tid >> 6) & 3, wr = (tid >> 8) & 1;
#pragma unroll
  for (int mm = 0; mm < 8; ++mm) {
    const int r = blockIdx.x * 256 + (mm >> 2) * 128 + wr * 64 + (mm & 3) * 16 + ((lane >> 4) << 2);
#pragma unroll
    for (int nn = 0; nn < 4; ++nn) {
      const int c = blockIdx.y * 256 + (nn >> 1) * 128 + wc * 32 + (nn & 1) * 16 + (lane & 15);
#pragma unroll
      for (int q = 0; q < 4; ++q) Sb[(size_t)(r + q) * NC + c] = acc[mm][nn][q];
    }
  }
}

// softmax over each row of S (2048 f32); write f16 att in-place (row stride 4096 u16)
__global__ __launch_bounds__(256) void softmax_rows(float* __restrict__ S) {
  float* Sr = S + (size_t)blockIdx.x * NC;
  const int t = threadIdx.x;
  const float4* Sv = (const float4*)Sr;
  const float4 v0 = Sv[2 * t];
  const float4 v1 = Sv[2 * t + 1];
  float mv = fmaxf(fmaxf(fmaxf(v0.x, v0.y), fmaxf(v0.z, v0.w)),
                   fmaxf(fmaxf(v1.x, v1.y), fmaxf(v1.z, v1.w)));
  mv = wave_max(mv);
  __shared__ float rm[4], rs[4];
  const int lane = t & 63, w = t >> 6;
  if (lane == 0) rm[w] = mv;
  __syncthreads();  // also guarantees all reads of Sr complete before in-place writes
  const float bm = fmaxf(fmaxf(rm[0], rm[1]), fmaxf(rm[2], rm[3]));
  const float e0 = __expf(v0.x - bm), e1 = __expf(v0.y - bm);
  const float e2 = __expf(v0.z - bm), e3 = __expf(v0.w - bm);
  const float e4 = __expf(v1.x - bm), e5 = __expf(v1.y - bm);
  const float e6 = __expf(v1.z - bm), e7 = __expf(v1.w - bm);
  float s = ((e0 + e1) + (e2 + e3)) + ((e4 + e5) + (e6 + e7));
  s = wave_sum(s);
  if (lane == 0) rs[w] = s;
  __syncthreads();
  const float inv = 1.f / ((rs[0] + rs[1]) + (rs[2] + rs[3]));
  u32x4 p;
  p.x = pack2(e0 * inv, e1 * inv);
  p.y = pack2(e2 * inv, e3 * inv);
  p.z = pack2(e4 * inv, e5 * inv);
  p.w = pack2(e6 * inv, e7 * inv);
  u16* ar = (u16*)Sr;
  *(u32x4*)(ar + t * 8) = p;
}

// out[b,i,d] = sum_j att[b,i,j] * Vt[b,d,j]   (A: att f16 ld=4096; B: Vt ld=2048)
__global__ __launch_bounds__(512, 1) void gemm_av(const u16* __restrict__ att,
                                                  const u16* __restrict__ Vt,
                                                  float* __restrict__ out) {
  __shared__ u16 lds[2][2][4][4096];
  const int tid = threadIdx.x;
  const int bz = blockIdx.z;
  f32x4 acc[8][4] = {};
  gemm256(att + ((size_t)bz * NC + blockIdx.x * 256) * (NC * 2), NC * 2,
          Vt + ((size_t)bz * ND + blockIdx.y * 256) * NC, NC, NC / 64, lds, tid, acc);
  float* Ob = out + (size_t)bz * NC * ND;
  const int lane = tid & 63, wc = (tid >> 6) & 3, wr = (tid >> 8) & 1;
#pragma unroll
  for (int mm = 0; mm < 8; ++mm) {
    const int r = blockIdx.x * 256 + (mm >> 2) * 128 + wr * 64 + (mm & 3) * 16 + ((lane >> 4) << 2);
#pragma unroll
    for (int nn = 0; nn < 4; ++nn) {
      const int c = blockIdx.y * 256 + (nn >> 1) * 128 + wc * 32 + (nn & 1) * 16 + (lane & 15);
#pragma unroll
      for (int q = 0; q < 4; ++q) Ob[(size_t)(r + q) * ND + c] = acc[mm][nn][q];
    }
  }
}

extern "C" void kernel_launch(void* const* d_in, const int* in_sizes, int n_in,
                              void* d_out, int out_size, void* d_ws, size_t ws_size,
                              hipStream_t stream) {
  (void)in_sizes; (void)n_in; (void)out_size; (void)ws_size;
  const float* x = (const float*)d_in[0];
  const float* Wk = (const float*)d_in[1];
  const float* Wq = (const float*)d_in[2];
  const float* Wv = (const float*)d_in[3];
  char* ws = (char*)d_ws;
  float* stats = (float*)ws;                    //        64 B
  u16* xn = (u16*)(ws + 256);                   //  25165824
  u16* Wb = (u16*)(ws + 25166080);              //   3538944
  u16* Qb = (u16*)(ws + 28705024);              //  25165824
  u16* Kb = (u16*)(ws + 53870848);              //  25165824
  u16* Vt = (u16*)(ws + 79036672);              //  25165824
  float* S = (float*)(ws + 104202496);          // 134217728 (end 238420224)
  float* out = (float*)d_out;

  hipMemsetAsync(stats, 0, 64, stream);
  ln_stats<<<dim3(64, 8), 256, 0, stream>>>(x, stats);
  ln_apply<<<6144, 256, 0, stream>>>(x, stats, xn);
  cast_w<<<864, 256, 0, stream>>>(Wk, Wq, Wv, Wb);
  gemm_proj<<<dim3(64, 3, 3), 512, 0, stream>>>(xn, Wb, Kb, Qb, Vt);
  gemm_qk<<<dim3(8, 8, 8), 512, 0, stream>>>(Qb, Kb, S);
  softmax_rows<<<16384, 256, 0, stream>>>(S);
  gemm_av<<<dim3(8, 3, 8), 512, 0, stream>>>((const u16*)S, Vt, out);
}

// Round 7
// 356.611 us; speedup vs baseline: 1.0736x; 1.0318x over previous
//
#include <hip/hip_runtime.h>
#include <stdint.h>

#define NB 8
#define NC 2048
#define ND 768
#define CD (NC * ND)  // 1572864
#define EPSV 1e-5f

typedef _Float16 f16;
typedef f16 f16x2 __attribute__((ext_vector_type(2)));
typedef f16 f16x8 __attribute__((ext_vector_type(8)));
typedef float f32x4 __attribute__((ext_vector_type(4)));
typedef unsigned short u16;
typedef unsigned int u32;
typedef u32 u32x2 __attribute__((ext_vector_type(2)));
typedef u32 u32x4 __attribute__((ext_vector_type(4)));

__device__ __forceinline__ u16 f2h(float f) {
  return __builtin_bit_cast(u16, (f16)f);  // v_cvt_f16_f32, RNE
}
__device__ __forceinline__ u32 pack2(float a, float b) {
  f16x2 h = {(f16)a, (f16)b};
  return __builtin_bit_cast(u32, h);
}

__device__ __forceinline__ float wave_sum(float v) {
#pragma unroll
  for (int o = 32; o > 0; o >>= 1) v += __shfl_down(v, o);
  return v;
}
__device__ __forceinline__ float wave_max(float v) {
#pragma unroll
  for (int o = 32; o > 0; o >>= 1) v = fmaxf(v, __shfl_down(v, o));
  return v;
}

// ---------------- LayerNorm over [C,D] per batch ----------------
__global__ __launch_bounds__(256) void ln_stats(const float* __restrict__ x,
                                                float* __restrict__ stats) {
  const int b = blockIdx.y;
  const float4* xb = (const float4*)(x + (size_t)b * CD);
  const int base = blockIdx.x * 6144;
  float s1 = 0.f, s2 = 0.f;
  for (int i = threadIdx.x; i < 6144; i += 256) {
    float4 v = xb[base + i];
    s1 += (v.x + v.y) + (v.z + v.w);
    s2 += (v.x * v.x + v.y * v.y) + (v.z * v.z + v.w * v.w);
  }
  s1 = wave_sum(s1);
  s2 = wave_sum(s2);
  __shared__ float r1[4], r2[4];
  const int lane = threadIdx.x & 63, w = threadIdx.x >> 6;
  if (lane == 0) { r1[w] = s1; r2[w] = s2; }
  __syncthreads();
  if (threadIdx.x == 0) {
    atomicAdd(&stats[b * 2], (r1[0] + r1[1]) + (r1[2] + r1[3]));
    atomicAdd(&stats[b * 2 + 1], (r2[0] + r2[1]) + (r2[2] + r2[3]));
  }
}

__global__ __launch_bounds__(256) void ln_apply(const float* __restrict__ x,
                                                const float* __restrict__ stats,
                                                u16* __restrict__ xn) {
  const size_t i = ((size_t)blockIdx.x * 256 + threadIdx.x) * 8;
  const int b = (int)(i / CD);
  const float mean = stats[b * 2] * (1.f / CD);
  const float var = stats[b * 2 + 1] * (1.f / CD) - mean * mean;
  const float rstd = rsqrtf(var + EPSV);
  const float4 v0 = *(const float4*)(x + i);
  const float4 v1 = *(const float4*)(x + i + 4);
  u32x4 p;
  p.x = pack2((v0.x - mean) * rstd, (v0.y - mean) * rstd);
  p.y = pack2((v0.z - mean) * rstd, (v0.w - mean) * rstd);
  p.z = pack2((v1.x - mean) * rstd, (v1.y - mean) * rstd);
  p.w = pack2((v1.z - mean) * rstd, (v1.w - mean) * rstd);
  *(u32x4*)(xn + i) = p;
}

__global__ __launch_bounds__(256) void cast_w(const float* __restrict__ Wk,
                                              const float* __restrict__ Wq,
                                              const float* __restrict__ Wv,
                                              u16* __restrict__ Wb) {
  const size_t i = ((size_t)blockIdx.x * 256 + threadIdx.x) * 8;
  const size_t WSZ = (size_t)ND * ND;
  const float* src;
  size_t off;
  if (i < WSZ) { src = Wk; off = i; }
  else if (i < 2 * WSZ) { src = Wq; off = i - WSZ; }
  else { src = Wv; off = i - 2 * WSZ; }
  const float4 v0 = *(const float4*)(src + off);
  const float4 v1 = *(const float4*)(src + off + 4);
  u32x4 p;
  p.x = pack2(v0.x, v0.y);
  p.y = pack2(v0.z, v0.w);
  p.z = pack2(v1.x, v1.y);
  p.w = pack2(v1.z, v1.w);
  *(u32x4*)(Wb + i) = p;
}

// ======== 256x256-tile, BK=64, 8-wave, counted-vmcnt superphase GEMM core (NT) ========
// LDS chunk: [128 rows][4 slots of 16B], slot swizzled s ^ ((rl>>1)&3); chunk = kk*2 + rowhalf.
__device__ __forceinline__ void stage_chunk(u16* dst, const u16* src, int ld, int tid) {
  const int rl = tid >> 2;
  const int sc = (tid & 3) ^ ((tid >> 3) & 3);  // inverse swizzle on global source
  const u16* gp = src + (size_t)rl * ld + sc * 8;
  __builtin_amdgcn_global_load_lds(
      (const __attribute__((address_space(1))) void*)gp,
      (__attribute__((address_space(3))) void*)(dst + tid * 8), 16, 0, 0);
}

__device__ __forceinline__ void mf16(f32x4 acc[8][4], int mb, const f16x8 a[4],
                                     const f16x8 b[4]) {
#pragma unroll
  for (int m = 0; m < 4; ++m)
#pragma unroll
    for (int n = 0; n < 4; ++n)
      acc[mb + m][n] =
          __builtin_amdgcn_mfma_f32_16x16x32_f16(a[m], b[n], acc[mb + m][n], 0, 0, 0);
}

// Per-wave C: rows (mm>>2)*128 + wr*64 + (mm&3)*16 + (lane>>4)*4 + q,
//            cols (nn>>1)*128 + wc*32 + (nn&1)*16 + (lane&15).
__device__ __forceinline__ void gemm256(const u16* __restrict__ A, int lda,
                                        const u16* __restrict__ B, int ldb, int nk,
                                        u16 (*lds)[2][4][4096], int tid,
                                        f32x4 acc[8][4]) {
  const int lane = tid & 63;
  const int wc = (tid >> 6) & 3;
  const int wr = (tid >> 8) & 1;
  const int fr = lane & 15;
  const int SL = (lane >> 4) ^ ((lane >> 1) & 3);  // swizzled 16B-slot
  int aoff[4], boff[4];
#pragma unroll
  for (int m = 0; m < 4; ++m) aoff[m] = (wr * 64 + m * 16 + fr) * 32 + SL * 8;
#pragma unroll
  for (int n = 0; n < 4; ++n) boff[n] = (wc * 32 + (n & 1) * 16 + fr) * 32 + SL * 8;

#define STG_A(BUF, T, KK)                                                         \
  do {                                                                            \
    const u16* s_ = A + (size_t)(T) * 64 + (KK) * 32;                             \
    stage_chunk(&lds[BUF][0][(KK) * 2 + 0][0], s_, lda, tid);                     \
    stage_chunk(&lds[BUF][0][(KK) * 2 + 1][0], s_ + (size_t)128 * lda, lda, tid); \
  } while (0)
#define STG_B(BUF, T, KK)                                                         \
  do {                                                                            \
    const u16* s_ = B + (size_t)(T) * 64 + (KK) * 32;                             \
    stage_chunk(&lds[BUF][1][(KK) * 2 + 0][0], s_, ldb, tid);                     \
    stage_chunk(&lds[BUF][1][(KK) * 2 + 1][0], s_ + (size_t)128 * ldb, ldb, tid); \
  } while (0)

  // prologue: tile 0 -> buf 0; group order = [A kk0 | B kk0 | A kk1 | B kk1]
  STG_A(0, 0, 0); STG_B(0, 0, 0); STG_A(0, 0, 1); STG_B(0, 0, 1);

  for (int t = 0; t < nk; ++t) {
    const int cur = t & 1, nb = cur ^ 1;
    const bool pre = (t + 1 < nk);
    f16x8 a0[4], a1[4], b[4];
    // ---- SP0: kk0 (chunks A0,A1,B0,B1 of tile t) ----
    asm volatile("s_waitcnt vmcnt(4)" ::: "memory");
    __builtin_amdgcn_s_barrier();
    __builtin_amdgcn_sched_barrier(0);
    if (pre) { STG_A(nb, t + 1, 0); STG_B(nb, t + 1, 0); }
#pragma unroll
    for (int m = 0; m < 4; ++m) a0[m] = *(const f16x8*)&lds[cur][0][0][aoff[m]];
#pragma unroll
    for (int m = 0; m < 4; ++m) a1[m] = *(const f16x8*)&lds[cur][0][1][aoff[m]];
    b[0] = *(const f16x8*)&lds[cur][1][0][boff[0]];
    b[1] = *(const f16x8*)&lds[cur][1][0][boff[1]];
    b[2] = *(const f16x8*)&lds[cur][1][1][boff[2]];
    b[3] = *(const f16x8*)&lds[cur][1][1][boff[3]];
    __builtin_amdgcn_s_setprio(1);
    mf16(acc, 0, a0, b);
    mf16(acc, 4, a1, b);
    __builtin_amdgcn_s_setprio(0);
    // ---- SP1: kk1 (chunks A2,A3,B2,B3 of tile t) ----
    if (pre) { asm volatile("s_waitcnt vmcnt(4)" ::: "memory"); }
    else     { asm volatile("s_waitcnt vmcnt(0)" ::: "memory"); }
    __builtin_amdgcn_s_barrier();
    __builtin_amdgcn_sched_barrier(0);
    if (pre) { STG_A(nb, t + 1, 1); STG_B(nb, t + 1, 1); }
#pragma unroll
    for (int m = 0; m < 4; ++m) a0[m] = *(const f16x8*)&lds[cur][0][2][aoff[m]];
#pragma unroll
    for (int m = 0; m < 4; ++m) a1[m] = *(const f16x8*)&lds[cur][0][3][aoff[m]];
    b[0] = *(const f16x8*)&lds[cur][1][2][boff[0]];
    b[1] = *(const f16x8*)&lds[cur][1][2][boff[1]];
    b[2] = *(const f16x8*)&lds[cur][1][3][boff[2]];
    b[3] = *(const f16x8*)&lds[cur][1][3][boff[3]];
    __builtin_amdgcn_s_setprio(1);
    mf16(acc, 0, a0, b);
    mf16(acc, 4, a1, b);
    __builtin_amdgcn_s_setprio(0);
  }
#undef STG_A
#undef STG_B
}

// z<2: SWAPPED (A=W rows d, B=xn rows c) -> q packs along d -> u32x2 stores into K/Q[c][d].
// z=2: A=xn rows c, B=Wv rows d -> q packs along c -> u32x2 stores into Vt[b][d][c].
__global__ __launch_bounds__(512, 1) void gemm_proj(const u16* __restrict__ xn,
                                                    const u16* __restrict__ Wb,
                                                    u16* __restrict__ Kb,
                                                    u16* __restrict__ Qb,
                                                    u16* __restrict__ Vt) {
  __shared__ u16 lds[2][2][4][4096];
  const int tid = threadIdx.x;
  const int xblk = blockIdx.x * 256;  // xn rows (token c)
  const int wblk = blockIdx.y * 256;  // W rows (out-dim d)
  const int z = blockIdx.z;
  f32x4 acc[8][4] = {};
  const int lane = tid & 63, wc = (tid >> 6) & 3, wr = (tid >> 8) & 1;
  if (z < 2) {
    gemm256(Wb + (size_t)z * ND * ND + (size_t)wblk * ND, ND, xn + (size_t)xblk * ND, ND,
            ND / 64, lds, tid, acc);
    u16* O = (z == 0) ? Kb : Qb;
#pragma unroll
    for (int mm = 0; mm < 8; ++mm) {
      const int d = wblk + (mm >> 2) * 128 + wr * 64 + (mm & 3) * 16 + ((lane >> 4) << 2);
#pragma unroll
      for (int nn = 0; nn < 4; ++nn) {
        const int c = xblk + (nn >> 1) * 128 + wc * 32 + (nn & 1) * 16 + (lane & 15);
        u32x2 p;
        p.x = pack2(acc[mm][nn][0], acc[mm][nn][1]);
        p.y = pack2(acc[mm][nn][2], acc[mm][nn][3]);
        *(u32x2*)(O + (size_t)c * ND + d) = p;
      }
    }
  } else {
    gemm256(xn + (size_t)xblk * ND, ND, Wb + (size_t)2 * ND * ND + (size_t)wblk * ND, ND,
            ND / 64, lds, tid, acc);
#pragma unroll
    for (int mm = 0; mm < 8; ++mm) {
      const int r = xblk + (mm >> 2) * 128 + wr * 64 + (mm & 3) * 16 + ((lane >> 4) << 2);
      const int bb = r >> 11;
      const int cc = r & 2047;
#pragma unroll
      for (int nn = 0; nn < 4; ++nn) {
        const int d = wblk + (nn >> 1) * 128 + wc * 32 + (nn & 1) * 16 + (lane & 15);
        u32x2 p;
        p.x = pack2(acc[mm][nn][0], acc[mm][nn][1]);
        p.y = pack2(acc[mm][nn][2], acc[mm][nn][3]);
        *(u32x2*)(Vt + ((size_t)bb * ND + d) * NC + cc) = p;
      }
    }
  }
}

// SWAPPED: A=K rows j, B=Q rows i -> q packs along j -> u32x2 f16 stores into S[i][j].
__global__ __launch_bounds__(512, 1) void gemm_qk(const u16* __restrict__ Qb,
                                                  const u16* __restrict__ Kb,
                                                  u16* __restrict__ S) {
  __shared__ u16 lds[2][2][4][4096];
  const int tid = threadIdx.x;
  const int bz = blockIdx.z;
  const int iblk = blockIdx.x * 256, jblk = blockIdx.y * 256;
  f32x4 acc[8][4] = {};
  gemm256(Kb + ((size_t)bz * NC + jblk) * ND, ND, Qb + ((size_t)bz * NC + iblk) * ND, ND,
          ND / 64, lds, tid, acc);
  u16* Sb = S + (size_t)bz * NC * NC;
  const int lane = tid & 63, wc = (tid >> 6) & 3, wr = (tid >> 8) & 1;
#pragma unroll
  for (int mm = 0; mm < 8; ++mm) {
    const int j = jblk + (mm >> 2) * 128 + wr * 64 + (mm & 3) * 16 + ((lane >> 4) << 2);
#pragma unroll
    for (int nn = 0; nn < 4; ++nn) {
      const int i = iblk + (nn >> 1) * 128 + wc * 32 + (nn & 1) * 16 + (lane & 15);
      u32x2 p;
      p.x = pack2(acc[mm][nn][0], acc[mm][nn][1]);
      p.y = pack2(acc[mm][nn][2], acc[mm][nn][3]);
      *(u32x2*)(Sb + (size_t)i * NC + j) = p;
    }
  }
}

// softmax over each row of S (2048 f16); write f16 att in-place
__global__ __launch_bounds__(256) void softmax_rows(u16* __restrict__ S) {
  u16* Sr = S + (size_t)blockIdx.x * NC;
  const int t = threadIdx.x;
  const f16x8 v = *(const f16x8*)(Sr + t * 8);
  float f[8];
#pragma unroll
  for (int j = 0; j < 8; ++j) f[j] = (float)v[j];
  float mv = fmaxf(fmaxf(fmaxf(f[0], f[1]), fmaxf(f[2], f[3])),
                   fmaxf(fmaxf(f[4], f[5]), fmaxf(f[6], f[7])));
  mv = wave_max(mv);
  __shared__ float rm[4], rs[4];
  const int lane = t & 63, w = t >> 6;
  if (lane == 0) rm[w] = mv;
  __syncthreads();
  const float bm = fmaxf(fmaxf(rm[0], rm[1]), fmaxf(rm[2], rm[3]));
  float e[8];
  float s = 0.f;
#pragma unroll
  for (int j = 0; j < 8; ++j) { e[j] = __expf(f[j] - bm); s += e[j]; }
  s = wave_sum(s);
  if (lane == 0) rs[w] = s;
  __syncthreads();
  const float inv = 1.f / ((rs[0] + rs[1]) + (rs[2] + rs[3]));
  u32x4 p;
  p.x = pack2(e[0] * inv, e[1] * inv);
  p.y = pack2(e[2] * inv, e[3] * inv);
  p.z = pack2(e[4] * inv, e[5] * inv);
  p.w = pack2(e[6] * inv, e[7] * inv);
  *(u32x4*)(Sr + t * 8) = p;
}

// SWAPPED: A=Vt rows d, B=att rows i -> q packs along d -> float4 stores into out[i][d].
__global__ __launch_bounds__(512, 1) void gemm_av(const u16* __restrict__ att,
                                                  const u16* __restrict__ Vt,
                                                  float* __restrict__ out) {
  __shared__ u16 lds[2][2][4][4096];
  const int tid = threadIdx.x;
  const int bz = blockIdx.z;
  const int iblk = blockIdx.x * 256, dblk = blockIdx.y * 256;
  f32x4 acc[8][4] = {};
  gemm256(Vt + ((size_t)bz * ND + dblk) * NC, NC, att + ((size_t)bz * NC + iblk) * NC, NC,
          NC / 64, lds, tid, acc);
  float* Ob = out + (size_t)bz * CD;
  const int lane = tid & 63, wc = (tid >> 6) & 3, wr = (tid >> 8) & 1;
#pragma unroll
  for (int mm = 0; mm < 8; ++mm) {
    const int d = dblk + (mm >> 2) * 128 + wr * 64 + (mm & 3) * 16 + ((lane >> 4) << 2);
#pragma unroll
    for (int nn = 0; nn < 4; ++nn) {
      const int i = iblk + (nn >> 1) * 128 + wc * 32 + (nn & 1) * 16 + (lane & 15);
      *(f32x4*)(Ob + (size_t)i * ND + d) = acc[mm][nn];
    }
  }
}

extern "C" void kernel_launch(void* const* d_in, const int* in_sizes, int n_in,
                              void* d_out, int out_size, void* d_ws, size_t ws_size,
                              hipStream_t stream) {
  (void)in_sizes; (void)n_in; (void)out_size; (void)ws_size;
  const float* x = (const float*)d_in[0];
  const float* Wk = (const float*)d_in[1];
  const float* Wq = (const float*)d_in[2];
  const float* Wv = (const float*)d_in[3];
  char* ws = (char*)d_ws;
  float* stats = (float*)ws;                    //        64 B
  u16* xn = (u16*)(ws + 256);                   //  25165824
  u16* Wb = (u16*)(ws + 25166080);              //   3538944
  u16* Qb = (u16*)(ws + 28705024);              //  25165824
  u16* Kb = (u16*)(ws + 53870848);              //  25165824
  u16* Vt = (u16*)(ws + 79036672);              //  25165824
  u16* S = (u16*)(ws + 104202496);              //  67108864 (end 171311360)
  float* out = (float*)d_out;

  hipMemsetAsync(stats, 0, 64, stream);
  ln_stats<<<dim3(64, 8), 256, 0, stream>>>(x, stats);
  ln_apply<<<6144, 256, 0, stream>>>(x, stats, xn);
  cast_w<<<864, 256, 0, stream>>>(Wk, Wq, Wv, Wb);
  gemm_proj<<<dim3(64, 3, 3), 512, 0, stream>>>(xn, Wb, Kb, Qb, Vt);
  gemm_qk<<<dim3(8, 8, 8), 512, 0, stream>>>(Qb, Kb, S);
  softmax_rows<<<16384, 256, 0, stream>>>(S);
  gemm_av<<<dim3(8, 3, 8), 512, 0, stream>>>(S, Vt, out);
}